// Round 12
// baseline (543.074 us; speedup 1.0000x reference)
//
#include <hip/hip_runtime.h>
#include <math.h>

#define N_PTS 8192
#define B_SZ 4
#define SEED_NUM 409
#define FPS_THREADS 256  // 4 waves, 1 per SIMD
#define LTOT 653  // 65+98+131+163+196

typedef float f2 __attribute__((ext_vector_type(2)));
typedef float f4 __attribute__((ext_vector_type(4)));

// Exact IEEE f32 squared distance, same op order as the reference:
// ((dx*dx + dy*dy) + dz*dz), no FMA contraction.
__device__ __forceinline__ float sqdist(float ax, float ay, float az,
                                        float bx, float by, float bz) {
  float dx = __fsub_rn(ax, bx);
  float dy = __fsub_rn(ay, by);
  float dz = __fsub_rn(az, bz);
  return __fadd_rn(__fadd_rn(__fmul_rn(dx, dx), __fmul_rn(dy, dy)),
                   __fmul_rn(dz, dz));
}

#define FOR16(M) \
  M(0) M(1) M(2) M(3) M(4) M(5) M(6) M(7) \
  M(8) M(9) M(10) M(11) M(12) M(13) M(14) M(15)

// ---- forced packed f32 ops (CDNA has NO v_pk_min/max_f32, so the compiler
// scalarizes any f2 chain containing min/max; asm pins the add/mul part
// packed; per-half semantics are exact IEEE rn = scalar ops) ----
__device__ __forceinline__ f2 pk_sub(f2 a, f2 b) {  // a - b
  f2 d;
  asm("v_pk_add_f32 %0, %1, %2 neg_lo:[0,1] neg_hi:[0,1]"
      : "=v"(d) : "v"(a), "v"(b));
  return d;
}
__device__ __forceinline__ f2 pk_mul(f2 a, f2 b) {
  f2 d;
  asm("v_pk_mul_f32 %0, %1, %2" : "=v"(d) : "v"(a), "v"(b));
  return d;
}
__device__ __forceinline__ f2 pk_add(f2 a, f2 b) {
  f2 d;
  asm("v_pk_add_f32 %0, %1, %2" : "=v"(d) : "v"(a), "v"(b));
  return d;
}

// u64 lane-move via two 32-bit DPP ops (ctrl fields are template constants).
// shr-stages: bound_ctrl=1 (OOB lanes read 0 — harmless for max of
// non-negative keys). bcast stages keep `old` in masked-off rows.
template <int CTRL>
__device__ __forceinline__ unsigned long long dpp_u64_bc1(
    unsigned long long k) {
  const unsigned lo2 = (unsigned)__builtin_amdgcn_update_dpp(
      0, (int)(unsigned)k, CTRL, 0xf, 0xf, true);
  const unsigned hi2 = (unsigned)__builtin_amdgcn_update_dpp(
      0, (int)(unsigned)(k >> 32), CTRL, 0xf, 0xf, true);
  return ((unsigned long long)hi2 << 32) | lo2;
}
template <int CTRL, int ROW_MASK>
__device__ __forceinline__ unsigned long long dpp_u64_keep(
    unsigned long long k) {
  const unsigned lo2 = (unsigned)__builtin_amdgcn_update_dpp(
      (int)(unsigned)k, (int)(unsigned)k, CTRL, ROW_MASK, 0xf, false);
  const unsigned hi2 = (unsigned)__builtin_amdgcn_update_dpp(
      (int)(unsigned)(k >> 32), (int)(unsigned)(k >> 32), CTRL, ROW_MASK, 0xf,
      false);
  return ((unsigned long long)hi2 << 32) | lo2;
}

// ---------------------------------------------------------------------------
// Kernel 1: farthest point sampling. One block per batch, 4 waves (1/SIMD).
// R12 = R10 structure (banked 327us) + two changes:
// (1) distance sub/mul/add chain forced to v_pk_* via inline asm (R9/R11
//     showed source-level f2 always scalarizes because CDNA lacks
//     v_pk_min/max_f32 and scalarization propagates backward; asm output is
//     opaque so min/track scalarize alone). ~8 fewer instr/pair.
// (2) cross-wave combine via double-buffered LDS ds_max_u64 slot instead of
//     4-key scan (lane63 atomicMax pre-barrier; tid0 resets the other slot
//     pre-barrier; one b64 broadcast read post-barrier).
// Tracking (R10, proven): per-half compare/select with ascending index order,
// strict '>' -> first-index ties; u64 DPP wave reduce; key =
// (f32bits(max)<<32)|(8191-idx) == exact jnp.argmax.
// ---------------------------------------------------------------------------
__global__ __launch_bounds__(FPS_THREADS, 1) void fps_kernel(
    const float* __restrict__ pcs, float* __restrict__ seeds,
    double* __restrict__ sums /*25 doubles*/) {
#pragma clang fp contract(off)
  const int b = blockIdx.x;
  const int tid = threadIdx.x;
  const int lane = tid & 63, wid = tid >> 6;  // 4 waves
  const float* base = pcs + (size_t)b * N_PTS * 3;

  if (b == 0 && tid < 25) sums[tid] = 0.0;  // zero totS[5]+accA[20]

  __shared__ f4 spts4[N_PTS];              // 128 KiB: winner-coord broadcast
  __shared__ float seedbuf[SEED_NUM * 3];  // 4.8 KiB: deferred seed output
  __shared__ unsigned long long slot[2];   // ds_max_u64 combine, dbl-buffered

  if (tid < 2) slot[tid] = 0ull;

  // pair j holds points i0 = tid + (2j)*256 and i1 = tid + (2j+1)*256
#define FPS_DECL(j) f2 px##j, py##j, pz##j, md##j;
  FOR16(FPS_DECL)
#undef FPS_DECL

#define FPS_INIT(j)                                   \
  {                                                   \
    const int i0 = tid + (2 * (j)) * FPS_THREADS;     \
    const int i1 = i0 + FPS_THREADS;                  \
    px##j = (f2){base[i0 * 3 + 0], base[i1 * 3 + 0]}; \
    py##j = (f2){base[i0 * 3 + 1], base[i1 * 3 + 1]}; \
    pz##j = (f2){base[i0 * 3 + 2], base[i1 * 3 + 2]}; \
    md##j = (f2){1e10f, 1e10f}; /* ref 1e10 exact */  \
    spts4[i0] = (f4){px##j.x, py##j.x, pz##j.x, 0.f}; \
    spts4[i1] = (f4){px##j.y, py##j.y, pz##j.y, 0.f}; \
  }
  FOR16(FPS_INIT)
#undef FPS_INIT

  // Pin coords in VGPRs (asm results can't be rematerialized from memory).
#define FPS_PIN(j) asm volatile("" : "+v"(px##j), "+v"(py##j), "+v"(pz##j));
  FOR16(FPS_PIN)
#undef FPS_PIN

  __syncthreads();  // order slot init (and spts4) before step-0 atomics

  float cx = base[0], cy = base[1], cz = base[2];

  for (int s = 0; s < SEED_NUM; ++s) {
    if (tid == 0) {
      seedbuf[s * 3 + 0] = cx;
      seedbuf[s * 3 + 1] = cy;
      seedbuf[s * 3 + 2] = cz;
      slot[(s + 1) & 1] = 0ull;  // reset next-step slot (pre-barrier)
    }
    const f2 ccx = (f2){cx, cx}, ccy = (f2){cy, cy}, ccz = (f2){cz, cz};
    float bv = -1.0f;
    int bi = 0;
    // ascending index order + strict '>' keeps the first index on ties.
#define FPS_UPD(j)                                                      \
  {                                                                     \
    const f2 dx = pk_sub(px##j, ccx);                                   \
    const f2 dy = pk_sub(py##j, ccy);                                   \
    const f2 dz = pk_sub(pz##j, ccz);                                   \
    const f2 t0 = pk_mul(dx, dx);                                       \
    const f2 t1 = pk_mul(dy, dy);                                       \
    const f2 t2 = pk_mul(dz, dz);                                       \
    const f2 d2 = pk_add(pk_add(t0, t1), t2);                           \
    const f2 m = __builtin_elementwise_min(md##j, d2);                  \
    md##j = m;                                                          \
    if (m.x > bv) { bv = m.x; bi = tid + (2 * (j)) * FPS_THREADS; }     \
    if (m.y > bv) { bv = m.y; bi = tid + (2 * (j) + 1) * FPS_THREADS; } \
  }
    FOR16(FPS_UPD)
#undef FPS_UPD
    // packed argmax key: bv >= 0 so f32 bits are monotone; u64 max ==
    // (max value, tie -> min index) == jnp.argmax semantics.
    unsigned long long key =
        ((unsigned long long)__float_as_uint(bv) << 32) |
        (unsigned long long)(unsigned)(N_PTS - 1 - bi);
    unsigned long long o;
    o = dpp_u64_bc1<0x111>(key);         key = (o > key) ? o : key;  // shr 1
    o = dpp_u64_bc1<0x112>(key);         key = (o > key) ? o : key;  // shr 2
    o = dpp_u64_bc1<0x114>(key);         key = (o > key) ? o : key;  // shr 4
    o = dpp_u64_bc1<0x118>(key);         key = (o > key) ? o : key;  // shr 8
    o = dpp_u64_keep<0x142, 0xa>(key);   key = (o > key) ? o : key;  // bcast15
    o = dpp_u64_keep<0x143, 0xc>(key);   key = (o > key) ? o : key;  // bcast31
    if (lane == 63) atomicMax(&slot[s & 1], key);  // ds_max_u64
    __syncthreads();
    const unsigned long long kmax = slot[s & 1];   // b64 broadcast read
    const int ci = N_PTS - 1 - (int)(unsigned)(kmax & 0xffffull);
    const f4 c = spts4[ci];  // one ds_read_b128, same-address broadcast
    cx = c.x;
    cy = c.y;
    cz = c.z;
  }

  // bulk seed writeback (ordered by the final in-loop barrier)
  __syncthreads();
  float* sg = seeds + (size_t)b * SEED_NUM * 3;
  for (int i = tid; i < SEED_NUM * 3; i += FPS_THREADS) sg[i] = seedbuf[i];
}

// ---------------------------------------------------------------------------
// Kernel 2: one block per group, ALL 5 percentages at once (unchanged —
// est. ~30-40 us). Order-free atomic-append collection (valid-sets nest, KNN
// is set-order-independent); ordered-recompaction fallback for the
// measure-zero cnt>K case; 4-thread/row two-min KNN with shfl_xor merge.
// ---------------------------------------------------------------------------
__global__ __launch_bounds__(256) void group_kernel(
    const float* __restrict__ pcs, const float* __restrict__ seeds,
    double* __restrict__ totS /*[5]*/, double* __restrict__ accA /*[5][4]*/) {
  const int g = blockIdx.x;  // 0 .. B*SEED_NUM-1
  const int b = g / SEED_NUM;
  const int tid = threadIdx.x;
  const int lane = tid & 63, wid = tid >> 6;

  const int Kc[5] = {65, 98, 131, 163, 196};
  const int off[5] = {0, 65, 163, 294, 457};
  const double Pd[5] = {0.004, 0.006, 0.008, 0.01, 0.012};
  float r2c[5], expnf[5], expdc[5];
#pragma unroll
  for (int p = 0; p < 5; ++p) {
    const double pd = Pd[p];
    const double rd = sqrt(pd);
    r2c[p] = (float)(rd * rd);                     // weak f32 cast of r*r
    const double expn_d = 8192.0 * pd;
    expnf[p] = (float)expn_d;
    expdc[p] = sqrtf((float)(M_PI / expn_d * pd));  // expect_dis (= sqrt(pi/N))
  }

  const float* base = pcs + (size_t)b * N_PTS * 3;
  const float* sp = seeds + (size_t)g * 3;
  const float sx = sp[0], sy = sp[1], sz = sp[2];

  __shared__ float lx[LTOT], ly[LTOT], lz[LTOT];
  __shared__ int cnt[5];
  __shared__ int wtot[4];     // fallback path only
  __shared__ double wsum[4];

  if (tid < 5) cnt[tid] = 0;
  __syncthreads();

  // ---- single barrier-free scan: d2 once, append to each nested list ----
  const float r2max = r2c[4];
  for (int i = tid; i < N_PTS; i += 256) {
    const float x = base[i * 3 + 0];
    const float y = base[i * 3 + 1];
    const float z = base[i * 3 + 2];
    const float d2 = sqdist(x, y, z, sx, sy, sz);
    if (d2 < r2max) {
#pragma unroll
      for (int p = 0; p < 5; ++p) {
        if (d2 < r2c[p]) {
          const int pos = atomicAdd(&cnt[p], 1);
          if (pos < Kc[p]) {
            lx[off[p] + pos] = x;
            ly[off[p] + pos] = y;
            lz[off[p] + pos] = z;
          }
        }
      }
    }
  }
  __syncthreads();

  // ---- rare fallback: cnt>K needs the K smallest indices (ordered) ----
#pragma unroll
  for (int p = 0; p < 5; ++p) {
    if (cnt[p] > Kc[p]) {  // block-uniform (LDS value, post-barrier)
      int run = 0;
      for (int base_i = 0; base_i < N_PTS; base_i += 256) {
        const int i = base_i + tid;
        const float x = base[i * 3 + 0];
        const float y = base[i * 3 + 1];
        const float z = base[i * 3 + 2];
        const float d2 = sqdist(x, y, z, sx, sy, sz);
        const bool valid = d2 < r2c[p];
        const unsigned long long m = __ballot(valid);
        if (lane == 0) wtot[wid] = __popcll(m);
        __syncthreads();
        int pos = run + __popcll(m & ((1ull << lane) - 1ull));
        for (int w = 0; w < wid; ++w) pos += wtot[w];
        if (valid && pos < Kc[p]) {
          lx[off[p] + pos] = x; ly[off[p] + pos] = y; lz[off[p] + pos] = z;
        }
        run += wtot[0] + wtot[1] + wtot[2] + wtot[3];
        __syncthreads();
      }
    }
  }

  // ---- KNN + clutter per percentage: 4 threads/row, shfl two-min merge ----
#pragma unroll
  for (int p = 0; p < 5; ++p) {
    const int gn = min(cnt[p], Kc[p]);  // gnum >= 1 (seed itself is in pcs)
    const float ed = expdc[p];
    const int lb = off[p];
    double localS = 0.0;
    for (int r0 = 0; r0 < gn; r0 += 64) {
      const int row = r0 + (tid >> 2);
      const int sub = tid & 3;
      float m1 = INFINITY, m2 = INFINITY;
      if (row < gn) {
        const float xi = lx[lb + row], yi = ly[lb + row], zi = lz[lb + row];
        for (int j = sub; j < gn; j += 4) {
          const float d2 = sqdist(xi, yi, zi, lx[lb + j], ly[lb + j], lz[lb + j]);
          if (d2 < m1) { m2 = m1; m1 = d2; }
          else if (d2 < m2) { m2 = d2; }
        }
      }
      // merge (m1,m2) pairs across the 4 sub-lanes (multiset two-min)
#pragma unroll
      for (int d = 1; d <= 2; d <<= 1) {
        const float om1 = __shfl_xor(m1, d);
        const float om2 = __shfl_xor(m2, d);
        const float lo = fminf(m1, om1);
        const float hi = fmaxf(m1, om1);
        m2 = fminf(fminf(m2, om2), hi);
        m1 = lo;
      }
      if (row < gn && sub == 0) {
        const float nn2 = (m2 > 1e37f) ? 0.0f : m2;  // inf (gn==1) -> 0
        const float nnd = (nn2 > 0.0f) ? sqrtf(nn2) : 0.0f;
        const float diff = __fsub_rn(nnd, ed);
        const float clut = __fdiv_rn(__fmul_rn(diff, diff),
                                     __fadd_rn(ed, 1e-12f));
        localS += (double)clut;
      }
    }
#pragma unroll
    for (int o = 32; o > 0; o >>= 1) localS += __shfl_down(localS, o);
    if (lane == 0) wsum[wid] = localS;
    __syncthreads();
    if (tid == 0) {
      const double S = wsum[0] + wsum[1] + wsum[2] + wsum[3];
      atomicAdd(&totS[p], S);
      const float gf = (float)gn;
      const float dd = __fsub_rn(gf, expnf[p]);
      const float imb = __fdiv_rn(__fmul_rn(dd, dd), expnf[p]);
      atomicAdd(&accA[p * 4 + b], (double)imb / (double)gf);
    }
    __syncthreads();  // wsum reused next p
  }
}

// ---------------------------------------------------------------------------
// Kernel 3: loss[b] = (1/5) * sum_p totS[p] * (accA[p][b] / 409)
// ---------------------------------------------------------------------------
__global__ void finalize_kernel(const double* __restrict__ totS,
                                const double* __restrict__ accA,
                                float* __restrict__ out) {
  const int b = threadIdx.x;
  if (b < B_SZ) {
    double acc = 0.0;
    for (int p = 0; p < 5; ++p)
      acc += totS[p] * (accA[p * 4 + b] / (double)SEED_NUM);
    out[b] = (float)(acc / 5.0);
  }
}

extern "C" void kernel_launch(void* const* d_in, const int* in_sizes, int n_in,
                              void* d_out, int out_size, void* d_ws,
                              size_t ws_size, hipStream_t stream) {
  (void)in_sizes; (void)n_in; (void)out_size; (void)ws_size;
  const float* pcs = (const float*)d_in[0];
  float* out = (float*)d_out;

  // ws layout: seeds (B*409*3 f32 = 19632 B, 8-aligned), then 25 doubles.
  float* seeds = (float*)d_ws;
  double* sums = (double*)((char*)d_ws + 19632);

  fps_kernel<<<B_SZ, FPS_THREADS, 0, stream>>>(pcs, seeds, sums);
  group_kernel<<<B_SZ * SEED_NUM, 256, 0, stream>>>(pcs, seeds, sums, sums + 5);
  finalize_kernel<<<1, 64, 0, stream>>>(sums, sums + 5, out);
}

// Round 13
// 490.528 us; speedup vs baseline: 1.1071x; 1.1071x over previous
//
#include <hip/hip_runtime.h>
#include <math.h>

#define N_PTS 8192
#define B_SZ 4
#define SEED_NUM 409
#define FPS_THREADS 256  // 4 waves, 1 per SIMD
#define LTOT 653  // 65+98+131+163+196

typedef float f2 __attribute__((ext_vector_type(2)));
typedef float f4 __attribute__((ext_vector_type(4)));
typedef unsigned long long ull;
typedef ull u64x2 __attribute__((ext_vector_type(2)));

// Exact IEEE f32 squared distance, same op order as the reference:
// ((dx*dx + dy*dy) + dz*dz), no FMA contraction.
__device__ __forceinline__ float sqdist(float ax, float ay, float az,
                                        float bx, float by, float bz) {
  float dx = __fsub_rn(ax, bx);
  float dy = __fsub_rn(ay, by);
  float dz = __fsub_rn(az, bz);
  return __fadd_rn(__fadd_rn(__fmul_rn(dx, dx), __fmul_rn(dy, dy)),
                   __fmul_rn(dz, dz));
}

#define FOR16(M) \
  M(0) M(1) M(2) M(3) M(4) M(5) M(6) M(7) \
  M(8) M(9) M(10) M(11) M(12) M(13) M(14) M(15)

// u64 lane-move via two 32-bit DPP ops (ctrl fields are template constants).
// shr-stages: bound_ctrl=1 (OOB lanes read 0 — harmless for max of
// non-negative keys). bcast stages keep `old` in masked-off rows.
template <int CTRL>
__device__ __forceinline__ ull dpp_u64_bc1(ull k) {
  const unsigned lo2 = (unsigned)__builtin_amdgcn_update_dpp(
      0, (int)(unsigned)k, CTRL, 0xf, 0xf, true);
  const unsigned hi2 = (unsigned)__builtin_amdgcn_update_dpp(
      0, (int)(unsigned)(k >> 32), CTRL, 0xf, 0xf, true);
  return ((ull)hi2 << 32) | lo2;
}
template <int CTRL, int ROW_MASK>
__device__ __forceinline__ ull dpp_u64_keep(ull k) {
  const unsigned lo2 = (unsigned)__builtin_amdgcn_update_dpp(
      (int)(unsigned)k, (int)(unsigned)k, CTRL, ROW_MASK, 0xf, false);
  const unsigned hi2 = (unsigned)__builtin_amdgcn_update_dpp(
      (int)(unsigned)(k >> 32), (int)(unsigned)(k >> 32), CTRL, ROW_MASK, 0xf,
      false);
  return ((ull)hi2 << 32) | lo2;
}

// ---------------------------------------------------------------------------
// Kernel 1: farthest point sampling. One block per batch, 4 waves (1/SIMD).
// R13 = exact R10 structure (banked 327us fps / 482 total) + ONE micro:
// 16B-aligned red[] and the post-barrier 4-key combine as two INDEPENDENT
// ds_read_b128 (back-to-back issue, ~130cyc) instead of an indexed scan.
// JOURNAL of failed theories (do not retry): R9/R11 source-level f2 packing
// — CDNA has no v_pk_min/max_f32, scalarization propagates backward, and the
// index-pass variant adds a serial tail (+42us). R12 pk inline-asm + LDS
// ds_max_u64 combine — register-pair shuffling and serialized atomics
// (+66us). R5 deferring the seed store — never on the critical path.
// Proven wins: 4 waves 1/SIMD (R10), DPP u64 argmax reduce (R8), asm "+v"
// coord pin (R4), LDS spts4 f4 winner broadcast (R10).
// ---------------------------------------------------------------------------
__global__ __launch_bounds__(FPS_THREADS, 1) void fps_kernel(
    const float* __restrict__ pcs, float* __restrict__ seeds,
    double* __restrict__ sums /*25 doubles*/) {
#pragma clang fp contract(off)
  const int b = blockIdx.x;
  const int tid = threadIdx.x;
  const int lane = tid & 63, wid = tid >> 6;  // 4 waves
  const float* base = pcs + (size_t)b * N_PTS * 3;

  if (b == 0 && tid < 25) sums[tid] = 0.0;  // zero totS[5]+accA[20]

  __shared__ f4 spts4[N_PTS];              // 128 KiB: winner-coord broadcast
  __shared__ float seedbuf[SEED_NUM * 3];  // 4.8 KiB: deferred seed output
  __shared__ __align__(16) ull red[2][4];  // per-wave keys, double-buffered

  // pair j holds points i0 = tid + (2j)*256 and i1 = tid + (2j+1)*256
#define FPS_DECL(j) f2 px##j, py##j, pz##j, md##j;
  FOR16(FPS_DECL)
#undef FPS_DECL

#define FPS_INIT(j)                                   \
  {                                                   \
    const int i0 = tid + (2 * (j)) * FPS_THREADS;     \
    const int i1 = i0 + FPS_THREADS;                  \
    px##j = (f2){base[i0 * 3 + 0], base[i1 * 3 + 0]}; \
    py##j = (f2){base[i0 * 3 + 1], base[i1 * 3 + 1]}; \
    pz##j = (f2){base[i0 * 3 + 2], base[i1 * 3 + 2]}; \
    md##j = (f2){1e10f, 1e10f}; /* ref 1e10 exact */  \
    spts4[i0] = (f4){px##j.x, py##j.x, pz##j.x, 0.f}; \
    spts4[i1] = (f4){px##j.y, py##j.y, pz##j.y, 0.f}; \
  }
  FOR16(FPS_INIT)
#undef FPS_INIT

  // Pin coords in VGPRs (asm results can't be rematerialized from memory).
#define FPS_PIN(j) asm volatile("" : "+v"(px##j), "+v"(py##j), "+v"(pz##j));
  FOR16(FPS_PIN)
#undef FPS_PIN

  float cx = base[0], cy = base[1], cz = base[2];

  for (int s = 0; s < SEED_NUM; ++s) {
    if (tid == 0) {
      seedbuf[s * 3 + 0] = cx;
      seedbuf[s * 3 + 1] = cy;
      seedbuf[s * 3 + 2] = cz;
    }
    const f2 ccx = (f2){cx, cx}, ccy = (f2){cy, cy}, ccz = (f2){cz, cz};
    float bv = -1.0f;
    int bi = 0;
    // ascending index order + strict '>' keeps the first index on ties.
#define FPS_UPD(j)                                                      \
  {                                                                     \
    const f2 dx = px##j - ccx;                                          \
    const f2 dy = py##j - ccy;                                          \
    const f2 dz = pz##j - ccz;                                          \
    const f2 t0 = dx * dx;                                              \
    const f2 t1 = dy * dy;                                              \
    const f2 t2 = dz * dz;                                              \
    const f2 d2 = (t0 + t1) + t2;                                       \
    const f2 m = __builtin_elementwise_min(md##j, d2);                  \
    md##j = m;                                                          \
    if (m.x > bv) { bv = m.x; bi = tid + (2 * (j)) * FPS_THREADS; }     \
    if (m.y > bv) { bv = m.y; bi = tid + (2 * (j) + 1) * FPS_THREADS; } \
  }
    FOR16(FPS_UPD)
#undef FPS_UPD
    // packed argmax key: bv >= 0 so f32 bits are monotone; u64 max ==
    // (max value, tie -> min index) == jnp.argmax semantics.
    ull key = ((ull)__float_as_uint(bv) << 32) |
              (ull)(unsigned)(N_PTS - 1 - bi);
    ull o;
    o = dpp_u64_bc1<0x111>(key);         key = (o > key) ? o : key;  // shr 1
    o = dpp_u64_bc1<0x112>(key);         key = (o > key) ? o : key;  // shr 2
    o = dpp_u64_bc1<0x114>(key);         key = (o > key) ? o : key;  // shr 4
    o = dpp_u64_bc1<0x118>(key);         key = (o > key) ? o : key;  // shr 8
    o = dpp_u64_keep<0x142, 0xa>(key);   key = (o > key) ? o : key;  // bcast15
    o = dpp_u64_keep<0x143, 0xc>(key);   key = (o > key) ? o : key;  // bcast31
    if (lane == 63) red[s & 1][wid] = key;
    __syncthreads();
    // 4-key combine via two independent ds_read_b128
    const u64x2* rp = (const u64x2*)(&red[s & 1][0]);
    const u64x2 r01 = rp[0];
    const u64x2 r23 = rp[1];
    ull ka = (r01.x > r01.y) ? r01.x : r01.y;
    const ull kb = (r23.x > r23.y) ? r23.x : r23.y;
    ka = (ka > kb) ? ka : kb;
    const int ci = N_PTS - 1 - (int)(unsigned)(ka & 0xffffull);
    const f4 c = spts4[ci];  // one ds_read_b128, same-address broadcast
    cx = c.x;
    cy = c.y;
    cz = c.z;
  }

  // bulk seed writeback (ordered by the final in-loop barrier)
  __syncthreads();
  float* sg = seeds + (size_t)b * SEED_NUM * 3;
  for (int i = tid; i < SEED_NUM * 3; i += FPS_THREADS) sg[i] = seedbuf[i];
}

// ---------------------------------------------------------------------------
// Kernel 2: one block per group, ALL 5 percentages at once (unchanged).
// Order-free atomic-append collection (valid-sets nest, KNN is
// set-order-independent); ordered-recompaction fallback for the measure-zero
// cnt>K case; 4-thread/row two-min KNN with shfl_xor merge.
// ---------------------------------------------------------------------------
__global__ __launch_bounds__(256) void group_kernel(
    const float* __restrict__ pcs, const float* __restrict__ seeds,
    double* __restrict__ totS /*[5]*/, double* __restrict__ accA /*[5][4]*/) {
  const int g = blockIdx.x;  // 0 .. B*SEED_NUM-1
  const int b = g / SEED_NUM;
  const int tid = threadIdx.x;
  const int lane = tid & 63, wid = tid >> 6;

  const int Kc[5] = {65, 98, 131, 163, 196};
  const int off[5] = {0, 65, 163, 294, 457};
  const double Pd[5] = {0.004, 0.006, 0.008, 0.01, 0.012};
  float r2c[5], expnf[5], expdc[5];
#pragma unroll
  for (int p = 0; p < 5; ++p) {
    const double pd = Pd[p];
    const double rd = sqrt(pd);
    r2c[p] = (float)(rd * rd);                     // weak f32 cast of r*r
    const double expn_d = 8192.0 * pd;
    expnf[p] = (float)expn_d;
    expdc[p] = sqrtf((float)(M_PI / expn_d * pd));  // expect_dis (= sqrt(pi/N))
  }

  const float* base = pcs + (size_t)b * N_PTS * 3;
  const float* sp = seeds + (size_t)g * 3;
  const float sx = sp[0], sy = sp[1], sz = sp[2];

  __shared__ float lx[LTOT], ly[LTOT], lz[LTOT];
  __shared__ int cnt[5];
  __shared__ int wtot[4];     // fallback path only
  __shared__ double wsum[4];

  if (tid < 5) cnt[tid] = 0;
  __syncthreads();

  // ---- single barrier-free scan: d2 once, append to each nested list ----
  const float r2max = r2c[4];
  for (int i = tid; i < N_PTS; i += 256) {
    const float x = base[i * 3 + 0];
    const float y = base[i * 3 + 1];
    const float z = base[i * 3 + 2];
    const float d2 = sqdist(x, y, z, sx, sy, sz);
    if (d2 < r2max) {
#pragma unroll
      for (int p = 0; p < 5; ++p) {
        if (d2 < r2c[p]) {
          const int pos = atomicAdd(&cnt[p], 1);
          if (pos < Kc[p]) {
            lx[off[p] + pos] = x;
            ly[off[p] + pos] = y;
            lz[off[p] + pos] = z;
          }
        }
      }
    }
  }
  __syncthreads();

  // ---- rare fallback: cnt>K needs the K smallest indices (ordered) ----
#pragma unroll
  for (int p = 0; p < 5; ++p) {
    if (cnt[p] > Kc[p]) {  // block-uniform (LDS value, post-barrier)
      int run = 0;
      for (int base_i = 0; base_i < N_PTS; base_i += 256) {
        const int i = base_i + tid;
        const float x = base[i * 3 + 0];
        const float y = base[i * 3 + 1];
        const float z = base[i * 3 + 2];
        const float d2 = sqdist(x, y, z, sx, sy, sz);
        const bool valid = d2 < r2c[p];
        const unsigned long long m = __ballot(valid);
        if (lane == 0) wtot[wid] = __popcll(m);
        __syncthreads();
        int pos = run + __popcll(m & ((1ull << lane) - 1ull));
        for (int w = 0; w < wid; ++w) pos += wtot[w];
        if (valid && pos < Kc[p]) {
          lx[off[p] + pos] = x; ly[off[p] + pos] = y; lz[off[p] + pos] = z;
        }
        run += wtot[0] + wtot[1] + wtot[2] + wtot[3];
        __syncthreads();
      }
    }
  }

  // ---- KNN + clutter per percentage: 4 threads/row, shfl two-min merge ----
#pragma unroll
  for (int p = 0; p < 5; ++p) {
    const int gn = min(cnt[p], Kc[p]);  // gnum >= 1 (seed itself is in pcs)
    const float ed = expdc[p];
    const int lb = off[p];
    double localS = 0.0;
    for (int r0 = 0; r0 < gn; r0 += 64) {
      const int row = r0 + (tid >> 2);
      const int sub = tid & 3;
      float m1 = INFINITY, m2 = INFINITY;
      if (row < gn) {
        const float xi = lx[lb + row], yi = ly[lb + row], zi = lz[lb + row];
        for (int j = sub; j < gn; j += 4) {
          const float d2 = sqdist(xi, yi, zi, lx[lb + j], ly[lb + j], lz[lb + j]);
          if (d2 < m1) { m2 = m1; m1 = d2; }
          else if (d2 < m2) { m2 = d2; }
        }
      }
      // merge (m1,m2) pairs across the 4 sub-lanes (multiset two-min)
#pragma unroll
      for (int d = 1; d <= 2; d <<= 1) {
        const float om1 = __shfl_xor(m1, d);
        const float om2 = __shfl_xor(m2, d);
        const float lo = fminf(m1, om1);
        const float hi = fmaxf(m1, om1);
        m2 = fminf(fminf(m2, om2), hi);
        m1 = lo;
      }
      if (row < gn && sub == 0) {
        const float nn2 = (m2 > 1e37f) ? 0.0f : m2;  // inf (gn==1) -> 0
        const float nnd = (nn2 > 0.0f) ? sqrtf(nn2) : 0.0f;
        const float diff = __fsub_rn(nnd, ed);
        const float clut = __fdiv_rn(__fmul_rn(diff, diff),
                                     __fadd_rn(ed, 1e-12f));
        localS += (double)clut;
      }
    }
#pragma unroll
    for (int o = 32; o > 0; o >>= 1) localS += __shfl_down(localS, o);
    if (lane == 0) wsum[wid] = localS;
    __syncthreads();
    if (tid == 0) {
      const double S = wsum[0] + wsum[1] + wsum[2] + wsum[3];
      atomicAdd(&totS[p], S);
      const float gf = (float)gn;
      const float dd = __fsub_rn(gf, expnf[p]);
      const float imb = __fdiv_rn(__fmul_rn(dd, dd), expnf[p]);
      atomicAdd(&accA[p * 4 + b], (double)imb / (double)gf);
    }
    __syncthreads();  // wsum reused next p
  }
}

// ---------------------------------------------------------------------------
// Kernel 3: loss[b] = (1/5) * sum_p totS[p] * (accA[p][b] / 409)
// ---------------------------------------------------------------------------
__global__ void finalize_kernel(const double* __restrict__ totS,
                                const double* __restrict__ accA,
                                float* __restrict__ out) {
  const int b = threadIdx.x;
  if (b < B_SZ) {
    double acc = 0.0;
    for (int p = 0; p < 5; ++p)
      acc += totS[p] * (accA[p * 4 + b] / (double)SEED_NUM);
    out[b] = (float)(acc / 5.0);
  }
}

extern "C" void kernel_launch(void* const* d_in, const int* in_sizes, int n_in,
                              void* d_out, int out_size, void* d_ws,
                              size_t ws_size, hipStream_t stream) {
  (void)in_sizes; (void)n_in; (void)out_size; (void)ws_size;
  const float* pcs = (const float*)d_in[0];
  float* out = (float*)d_out;

  // ws layout: seeds (B*409*3 f32 = 19632 B, 8-aligned), then 25 doubles.
  float* seeds = (float*)d_ws;
  double* sums = (double*)((char*)d_ws + 19632);

  fps_kernel<<<B_SZ, FPS_THREADS, 0, stream>>>(pcs, seeds, sums);
  group_kernel<<<B_SZ * SEED_NUM, 256, 0, stream>>>(pcs, seeds, sums, sums + 5);
  finalize_kernel<<<1, 64, 0, stream>>>(sums, sums + 5, out);
}